// Round 1
// baseline (148.342 us; speedup 1.0000x reference)
//
#include <hip/hip_runtime.h>

namespace {
constexpr int BLOCK = 256;
constexpr int ROWS_PER_TILE = 1024;
constexpr int NACC = 22;
// acc layout: [0..4]=counts, [5..8]=class_loss(0..3), [9..12]=loss_neg(0..3),
//             [13..16]=conf_li(0..3), [17..20]=conf_nsel(0..3), [21]=li_n
constexpr float EPSF = 1e-9f;
constexpr float THRF = 0.5f;
constexpr float WPF = 4.0f;
}

__device__ __forceinline__ float wave_reduce(float v) {
#pragma unroll
    for (int o = 32; o > 0; o >>= 1) v += __shfl_down(v, o, 64);
    return v;
}

__global__ __launch_bounds__(BLOCK) void mpu_main(const float* __restrict__ x,
                                                  const int* __restrict__ t,
                                                  float* __restrict__ acc, int N) {
    __shared__ float lds[ROWS_PER_TILE * 5];           // 20 KB tile of x
    __shared__ float red[BLOCK / 64][NACC];

    float a[NACC];
#pragma unroll
    for (int j = 0; j < NACC; ++j) a[j] = 0.0f;

    const int tid = threadIdx.x;
    const int numTiles = (N + ROWS_PER_TILE - 1) / ROWS_PER_TILE;

    for (int tile = blockIdx.x; tile < numTiles; tile += gridDim.x) {
        const long long rowBase = (long long)tile * ROWS_PER_TILE;
        const int rows = min(ROWS_PER_TILE, (int)((long long)N - rowBase));
        const int nFloats = rows * 5;
        const float* src = x + rowBase * 5;            // byte offset 20480*tile, 16B aligned
        const int n4 = nFloats >> 2;
        const float4* src4 = reinterpret_cast<const float4*>(src);
        float4* dst4 = reinterpret_cast<float4*>(lds);
        for (int i = tid; i < n4; i += BLOCK) dst4[i] = src4[i];
        for (int i = (n4 << 2) + tid; i < nFloats; i += BLOCK) lds[i] = src[i];
        __syncthreads();

        for (int k = tid; k < rows; k += BLOCK) {
            // row stride 5 floats: bank = (5k)%32, coprime -> conflict-free
            const float x0 = lds[k * 5 + 0], x1 = lds[k * 5 + 1], x2 = lds[k * 5 + 2],
                        x3 = lds[k * 5 + 3], x4 = lds[k * 5 + 4];
            const int tc = t[rowBase + k];

            const float mx = fmaxf(fmaxf(fmaxf(x0, x1), fmaxf(x2, x3)), x4);
            const float e0 = __expf(x0 - mx), e1 = __expf(x1 - mx),
                        e2 = __expf(x2 - mx), e3 = __expf(x3 - mx),
                        e4 = __expf(x4 - mx);
            const float r = 1.0f / (e0 + e1 + e2 + e3 + e4);
            const float p0 = e0 * r, p1 = e1 * r, p2 = e2 * r, p3 = e3 * r, p4 = e4 * r;

            const float nln = -__logf(p4 + EPSF);              // -log(p_neg + eps)
            const float pt = (tc == 0) ? p0 : (tc == 1) ? p1 : (tc == 2) ? p2
                           : (tc == 3) ? p3 : p4;
            const float nlt = -__logf(pt + EPSF);              // -log(p_t + eps)

            const bool is0 = (tc == 0), is1 = (tc == 1), is2 = (tc == 2),
                       is3 = (tc == 3), is4 = (tc == 4);

            // counts
            a[0] += is0 ? 1.0f : 0.0f;
            a[1] += is1 ? 1.0f : 0.0f;
            a[2] += is2 ? 1.0f : 0.0f;
            a[3] += is3 ? 1.0f : 0.0f;
            a[4] += is4 ? 1.0f : 0.0f;
            // class losses (positive classes only)
            a[5] += is0 ? nlt : 0.0f;
            a[6] += is1 ? nlt : 0.0f;
            a[7] += is2 ? nlt : 0.0f;
            a[8] += is3 ? nlt : 0.0f;
            // loss_neg per positive class
            a[9]  += is0 ? nln : 0.0f;
            a[10] += is1 ? nln : 0.0f;
            a[11] += is2 ? nln : 0.0f;
            a[12] += is3 ? nln : 0.0f;
            // conf terms: only class i==tc can satisfy (p_i>THR & t==i), so one div
            const bool sel = (pt > THRF);
            const float confv = sel ? (nln / pt) : 0.0f;
            const float confn = sel ? 1.0f : 0.0f;
            a[13] += is0 ? confv : 0.0f;
            a[14] += is1 ? confv : 0.0f;
            a[15] += is2 ? confv : 0.0f;
            a[16] += is3 ? confv : 0.0f;
            a[17] += is0 ? confn : 0.0f;
            a[18] += is1 ? confn : 0.0f;
            a[19] += is2 ? confn : 0.0f;
            a[20] += is3 ? confn : 0.0f;
            // negative conf: all(p<=THR) & t==4
            const bool alle = (p0 <= THRF) && (p1 <= THRF) && (p2 <= THRF) &&
                              (p3 <= THRF) && (p4 <= THRF);
            a[21] += (is4 && alle) ? nln : 0.0f;
        }
        __syncthreads();
    }

    // block reduction: wave shuffle -> LDS -> 22 atomics per block
    const int wave = tid >> 6;
    const int lane = tid & 63;
#pragma unroll
    for (int j = 0; j < NACC; ++j) {
        const float v = wave_reduce(a[j]);
        if (lane == 0) red[wave][j] = v;
    }
    __syncthreads();
    if (tid < NACC) {
        float v = red[0][tid] + red[1][tid] + red[2][tid] + red[3][tid];
        atomicAdd(&acc[tid], v);
    }
}

__global__ void mpu_final(const float* __restrict__ acc, float* __restrict__ out, int N) {
    if (threadIdx.x == 0 && blockIdx.x == 0) {
        const float invN = 1.0f / (float)N;
        float risk1 = 0.0f, risk2 = 0.0f, risk3 = 0.0f;
#pragma unroll
        for (int i = 0; i < 4; ++i) {
            const float cnt = acc[i];
            const float prior = cnt * invN;
            const float denom = fmaxf(1.0f, cnt);
            risk1 += prior * acc[5 + i] / denom;
            risk2 += prior * (acc[13 + i] / fmaxf(acc[17 + i], 1.0f));
            risk3 += prior * acc[9 + i] / denom;
        }
        const float risk4 = acc[21] / fmaxf(acc[4], 1.0f);
        float pos = WPF * (risk1 + risk2 - risk3);
        if (pos < 0.0f) pos = 0.0f;
        out[0] = pos + risk4;
    }
}

extern "C" void kernel_launch(void* const* d_in, const int* in_sizes, int n_in,
                              void* d_out, int out_size, void* d_ws, size_t ws_size,
                              hipStream_t stream) {
    const float* x = (const float*)d_in[0];
    const int* t = (const int*)d_in[1];
    float* out = (float*)d_out;
    float* acc = (float*)d_ws;
    const int N = in_sizes[1];   // t has N elements; x has N*5

    hipMemsetAsync(acc, 0, NACC * sizeof(float), stream);

    const int numTiles = (N + ROWS_PER_TILE - 1) / ROWS_PER_TILE;
    const int grid = numTiles < 1024 ? numTiles : 1024;
    mpu_main<<<grid, BLOCK, 0, stream>>>(x, t, acc, N);
    mpu_final<<<1, 64, 0, stream>>>(acc, out, N);
}